// Round 1
// baseline (14873.453 us; speedup 1.0000x reference)
//
#include <hip/hip_runtime.h>

#define NU 200000
#define NI 200000
#define H 64
#define NL 2
#define NE 4000000
#define NP 100000
#define EPSF 1e-5f

// ---------------- degree counts ----------------
__global__ __launch_bounds__(256) void count_kernel(
    const int* __restrict__ src, const int* __restrict__ dst,
    float* __restrict__ deg_u, float* __restrict__ deg_i, int n)
{
    int e = blockIdx.x * blockDim.x + threadIdx.x;
    if (e >= n) return;
    unsafeAtomicAdd(&deg_u[src[e]], 1.0f);
    unsafeAtomicAdd(&deg_i[dst[e]], 1.0f);
}

// ---------------- edge scatter (both directions, old features) ----------------
// 16 threads per edge, each handles one float4 chunk of the 64-float row.
__global__ __launch_bounds__(256) void scatter_kernel(
    const int* __restrict__ src, const int* __restrict__ dst,
    const float4* __restrict__ xu, const float4* __restrict__ xi,
    float* __restrict__ agg_u, float* __restrict__ agg_i, int n)
{
    long long t = (long long)blockIdx.x * blockDim.x + threadIdx.x;
    int e = (int)(t >> 4);
    int q = (int)(t & 15);
    if (e >= n) return;
    int s = src[e];
    int d = dst[e];
    // item row -> agg_u[src], user row -> agg_i[dst]
    float4 vi = xi[d * 16 + q];
    float4 vu = xu[s * 16 + q];
    float* au = agg_u + (size_t)s * H + q * 4;
    float* ai = agg_i + (size_t)d * H + q * 4;
    unsafeAtomicAdd(au + 0, vi.x);
    unsafeAtomicAdd(au + 1, vi.y);
    unsafeAtomicAdd(au + 2, vi.z);
    unsafeAtomicAdd(au + 3, vi.w);
    unsafeAtomicAdd(ai + 0, vu.x);
    unsafeAtomicAdd(ai + 1, vu.y);
    unsafeAtomicAdd(ai + 2, vu.z);
    unsafeAtomicAdd(ai + 3, vu.w);
}

// ---------------- fused node update: relu(bn(agg/deg @ Wll + bll + x @ Wlr)) ----------------
// 64 nodes per block; 4 nodes in flight per pass (one per 64-lane group).
// x_out may alias agg (row is staged to LDS before the write).
__global__ __launch_bounds__(256) void update_kernel(
    const float* __restrict__ agg, const float* __restrict__ x_in,
    float* __restrict__ x_out, const float* __restrict__ deg,
    const float* __restrict__ Wll, const float* __restrict__ bll,
    const float* __restrict__ Wlr,
    const float* __restrict__ bng, const float* __restrict__ bnb,
    const float* __restrict__ bnm, const float* __restrict__ bnv,
    int n_nodes)
{
    __shared__ float sWll[64 * 64];
    __shared__ float sWlr[64 * 64];
    __shared__ float sA[4][65];
    __shared__ float sX[4][65];
    int tid = threadIdx.x;
    for (int i = tid; i < 4096; i += 256) {
        sWll[i] = Wll[i];
        sWlr[i] = Wlr[i];
    }
    __syncthreads();
    int g = tid >> 6, j = tid & 63;
    float gj = bng[j], bj = bnb[j], mj = bnm[j];
    float rj = rsqrtf(bnv[j] + EPSF);
    float blj = bll[j];
    int base = blockIdx.x * 64;
    for (int nb = 0; nb < 64; nb += 4) {
        int node = base + nb + g;
        bool valid = node < n_nodes;
        if (valid) {
            sA[g][j] = agg[(size_t)node * H + j];
            sX[g][j] = x_in[(size_t)node * H + j];
        }
        __syncthreads();
        if (valid) {
            float accA = 0.f, accX = 0.f;
#pragma unroll
            for (int k = 0; k < 64; ++k) {
                accA = fmaf(sA[g][k], sWll[k * 64 + j], accA);
                accX = fmaf(sX[g][k], sWlr[k * 64 + j], accX);
            }
            float dv = deg[node];
            float inv = 1.0f / fmaxf(dv, 1.0f);
            float val = accA * inv + blj + accX;
            val = (val - mj) * rj * gj + bj;
            x_out[(size_t)node * H + j] = fmaxf(val, 0.f);
        }
        __syncthreads();
    }
}

// ---------------- MLP head: one wave per pair ----------------
__global__ __launch_bounds__(256) void mlp_kernel(
    const int* __restrict__ eli,
    const float* __restrict__ xu, const float* __restrict__ xi,
    const float* __restrict__ fc1w, const float* __restrict__ fc1b,
    const float* __restrict__ fc2w, const float* __restrict__ fc2b,
    float* __restrict__ out, int n)
{
    __shared__ float sW1[128 * 64];
    __shared__ float sU[4][65];
    __shared__ float sI[4][65];
    int tid = threadIdx.x;
    for (int i = tid; i < 8192; i += 256) sW1[i] = fc1w[i];
    __syncthreads();
    int w = tid >> 6, j = tid & 63;
    int p = blockIdx.x * 4 + w;
    bool valid = p < n;
    if (valid) {
        int ui = eli[p];
        int ii = eli[NP + p];
        sU[w][j] = xu[(size_t)ui * H + j];
        sI[w][j] = xi[(size_t)ii * H + j];
    }
    __syncthreads();
    float h = 0.f;
    if (valid) {
        float acc = fc1b[j];
#pragma unroll
        for (int k = 0; k < 64; ++k) acc = fmaf(sU[w][k], sW1[k * 64 + j], acc);
#pragma unroll
        for (int k = 0; k < 64; ++k) acc = fmaf(sI[w][k], sW1[(64 + k) * 64 + j], acc);
        h = fmaxf(acc, 0.f);
    }
    float p0 = h * fc2w[j * 4 + 0];
    float p1 = h * fc2w[j * 4 + 1];
    float p2 = h * fc2w[j * 4 + 2];
    float p3 = h * fc2w[j * 4 + 3];
#pragma unroll
    for (int off = 32; off >= 1; off >>= 1) {
        p0 += __shfl_xor(p0, off);
        p1 += __shfl_xor(p1, off);
        p2 += __shfl_xor(p2, off);
        p3 += __shfl_xor(p3, off);
    }
    if (valid && j == 0) {
        out[(size_t)p * 4 + 0] = p0 + fc2b[0];
        out[(size_t)p * 4 + 1] = p1 + fc2b[1];
        out[(size_t)p * 4 + 2] = p2 + fc2b[2];
        out[(size_t)p * 4 + 3] = p3 + fc2b[3];
    }
}

extern "C" void kernel_launch(void* const* d_in, const int* in_sizes, int n_in,
                              void* d_out, int out_size, void* d_ws, size_t ws_size,
                              hipStream_t stream) {
    const int*   edge_index = (const int*)d_in[0];
    const int*   eli        = (const int*)d_in[1];
    const float* user_emb   = (const float*)d_in[2];
    const float* item_emb   = (const float*)d_in[3];
    const float* u_ll_w     = (const float*)d_in[4];
    const float* u_ll_b     = (const float*)d_in[5];
    const float* u_lr_w     = (const float*)d_in[6];
    const float* i_ll_w     = (const float*)d_in[7];
    const float* i_ll_b     = (const float*)d_in[8];
    const float* i_lr_w     = (const float*)d_in[9];
    const float* u_bn_g     = (const float*)d_in[10];
    const float* u_bn_b     = (const float*)d_in[11];
    const float* u_bn_m     = (const float*)d_in[12];
    const float* u_bn_v     = (const float*)d_in[13];
    const float* i_bn_g     = (const float*)d_in[14];
    const float* i_bn_b     = (const float*)d_in[15];
    const float* i_bn_m     = (const float*)d_in[16];
    const float* i_bn_v     = (const float*)d_in[17];
    const float* fc1_w      = (const float*)d_in[18];
    const float* fc1_b      = (const float*)d_in[19];
    const float* fc2_w      = (const float*)d_in[20];
    const float* fc2_b      = (const float*)d_in[21];
    float* out = (float*)d_out;

    const int* src = edge_index;
    const int* dst = edge_index + NE;

    // workspace layout
    char* w = (char*)d_ws;
    float* deg_u = (float*)w;                 w += (size_t)NU * 4;
    float* deg_i = (float*)w;                 w += (size_t)NI * 4;
    float* bufA_u = (float*)w;                w += (size_t)NU * H * 4;
    float* bufA_i = (float*)w;                w += (size_t)NI * H * 4;
    float* bufB_u = (float*)w;                w += (size_t)NU * H * 4;
    float* bufB_i = (float*)w;                w += (size_t)NI * H * 4;

    // degrees (same for both layers)
    hipMemsetAsync(deg_u, 0, (size_t)(NU + NI) * 4, stream);
    count_kernel<<<(NE + 255) / 256, 256, 0, stream>>>(src, dst, deg_u, deg_i, NE);

    const int scatter_blocks = (int)(((long long)NE * 16 + 255) / 256);

    // ---- layer 0 (reads embeddings from d_in) ----
    hipMemsetAsync(bufA_u, 0, (size_t)(NU + NI) * H * 4, stream);
    scatter_kernel<<<scatter_blocks, 256, 0, stream>>>(
        src, dst, (const float4*)user_emb, (const float4*)item_emb, bufA_u, bufA_i, NE);
    update_kernel<<<(NU + 63) / 64, 256, 0, stream>>>(
        bufA_u, user_emb, bufA_u, deg_u,
        u_ll_w, u_ll_b, u_lr_w,
        u_bn_g, u_bn_b, u_bn_m, u_bn_v, NU);
    update_kernel<<<(NI + 63) / 64, 256, 0, stream>>>(
        bufA_i, item_emb, bufA_i, deg_i,
        i_ll_w, i_ll_b, i_lr_w,
        i_bn_g, i_bn_b, i_bn_m, i_bn_v, NI);

    // ---- layer 1 (reads bufA, writes bufB in-place over agg) ----
    hipMemsetAsync(bufB_u, 0, (size_t)(NU + NI) * H * 4, stream);
    scatter_kernel<<<scatter_blocks, 256, 0, stream>>>(
        src, dst, (const float4*)bufA_u, (const float4*)bufA_i, bufB_u, bufB_i, NE);
    update_kernel<<<(NU + 63) / 64, 256, 0, stream>>>(
        bufB_u, bufA_u, bufB_u, deg_u,
        u_ll_w + H * H, u_ll_b + H, u_lr_w + H * H,
        u_bn_g + H, u_bn_b + H, u_bn_m + H, u_bn_v + H, NU);
    update_kernel<<<(NI + 63) / 64, 256, 0, stream>>>(
        bufB_i, bufA_i, bufB_i, deg_i,
        i_ll_w + H * H, i_ll_b + H, i_lr_w + H * H,
        i_bn_g + H, i_bn_b + H, i_bn_m + H, i_bn_v + H, NI);

    // ---- MLP head ----
    mlp_kernel<<<(NP + 3) / 4, 256, 0, stream>>>(
        eli, bufB_u, bufB_i, fc1_w, fc1_b, fc2_w, fc2_b, out, NP);
}

// Round 2
// 2255.896 us; speedup vs baseline: 6.5931x; 6.5931x over previous
//
#include <hip/hip_runtime.h>

#define NU 200000
#define NI 200000
#define NN 400000   // NU + NI
#define H 64
#define NE 4000000
#define NP 100000
#define EPSF 1e-5f

// ---------------- CSR build: counts ----------------
__global__ __launch_bounds__(256) void count_kernel(
    const int* __restrict__ src, const int* __restrict__ dst,
    int* __restrict__ cnt, int n)
{
    int e = blockIdx.x * blockDim.x + threadIdx.x;
    if (e >= n) return;
    atomicAdd(&cnt[src[e]], 1);        // user side: edges grouped by src
    atomicAdd(&cnt[NU + dst[e]], 1);   // item side: edges grouped by dst
}

// ---------------- scan (3-pass, 1024/block) ----------------
__global__ __launch_bounds__(1024) void scan1_kernel(
    const int* __restrict__ cnt, int* __restrict__ off,
    int* __restrict__ bsum, int n)
{
    __shared__ int s[1024];
    int i = blockIdx.x * 1024 + threadIdx.x;
    int v = (i < n) ? cnt[i] : 0;
    s[threadIdx.x] = v;
    __syncthreads();
    for (int d = 1; d < 1024; d <<= 1) {
        int t = (threadIdx.x >= d) ? s[threadIdx.x - d] : 0;
        __syncthreads();
        s[threadIdx.x] += t;
        __syncthreads();
    }
    if (i < n) off[i + 1] = s[threadIdx.x];
    if (threadIdx.x == 1023) bsum[blockIdx.x] = s[1023];
}

__global__ __launch_bounds__(1024) void scan2_kernel(
    int* __restrict__ bsum, int* __restrict__ bpre, int nb)
{
    __shared__ int s[1024];
    int v = (threadIdx.x < nb) ? bsum[threadIdx.x] : 0;
    s[threadIdx.x] = v;
    __syncthreads();
    for (int d = 1; d < 1024; d <<= 1) {
        int t = (threadIdx.x >= d) ? s[threadIdx.x - d] : 0;
        __syncthreads();
        s[threadIdx.x] += t;
        __syncthreads();
    }
    if (threadIdx.x < nb) bpre[threadIdx.x] = s[threadIdx.x] - v;  // exclusive
}

__global__ __launch_bounds__(1024) void scan3_kernel(
    int* __restrict__ off, const int* __restrict__ bpre, int n)
{
    int i = blockIdx.x * 1024 + threadIdx.x;
    if (i < n) off[i + 1] += bpre[blockIdx.x];
    if (i == 0) off[0] = 0;
}

// ---------------- CSR fill ----------------
__global__ __launch_bounds__(256) void fill_kernel(
    const int* __restrict__ src, const int* __restrict__ dst,
    const int* __restrict__ off, int* __restrict__ cur,
    int* __restrict__ adj, int n)
{
    int e = blockIdx.x * blockDim.x + threadIdx.x;
    if (e >= n) return;
    int s = src[e], d = dst[e];
    int p = off[s] + atomicAdd(&cur[s], 1);
    adj[p] = d;                                  // user u's neighbor list: item ids
    int q = off[NU + d] + atomicAdd(&cur[NU + d], 1);
    adj[q] = s;                                  // item i's neighbor list: user ids
}

// ---------------- pull aggregation: one wave per node, writes the MEAN ----------------
__global__ __launch_bounds__(256) void pull_kernel(
    const int* __restrict__ off, const int* __restrict__ adj,
    const float* __restrict__ xu, const float* __restrict__ xi,
    float* __restrict__ agg_u, float* __restrict__ agg_i)
{
    int wid = (int)((blockIdx.x * 256 + threadIdx.x) >> 6);
    int lane = threadIdx.x & 63;
    if (wid >= NN) return;
    const float* table;
    float* out;
    int node;
    if (wid < NU) { node = wid;      table = xi; out = agg_u; }
    else          { node = wid - NU; table = xu; out = agg_i; }
    int beg = off[wid], end = off[wid + 1];
    float a0 = 0.f, a1 = 0.f, a2 = 0.f, a3 = 0.f;
    for (int k = beg; k < end; k += 64) {
        int nk = min(64, end - k);
        int nb = (lane < nk) ? adj[k + lane] : 0;
        int t = 0;
        for (; t + 4 <= nk; t += 4) {
            int n0 = __shfl(nb, t);
            int n1 = __shfl(nb, t + 1);
            int n2 = __shfl(nb, t + 2);
            int n3 = __shfl(nb, t + 3);
            a0 += table[(size_t)n0 * H + lane];
            a1 += table[(size_t)n1 * H + lane];
            a2 += table[(size_t)n2 * H + lane];
            a3 += table[(size_t)n3 * H + lane];
        }
        for (; t < nk; ++t)
            a0 += table[(size_t)__shfl(nb, t) * H + lane];
    }
    float s = (a0 + a1) + (a2 + a3);
    int deg = end - beg;
    out[(size_t)node * H + lane] = s / fmaxf((float)deg, 1.0f);
}

// ---------------- fused node update: relu(bn(agg_mean @ Wll + bll + x @ Wlr)) ----------------
__global__ __launch_bounds__(256) void update_kernel(
    const float* __restrict__ agg, const float* __restrict__ x_in,
    float* __restrict__ x_out,
    const float* __restrict__ Wll, const float* __restrict__ bll,
    const float* __restrict__ Wlr,
    const float* __restrict__ bng, const float* __restrict__ bnb,
    const float* __restrict__ bnm, const float* __restrict__ bnv,
    int n_nodes)
{
    __shared__ float sWll[64 * 64];
    __shared__ float sWlr[64 * 64];
    __shared__ float sA[4][65];
    __shared__ float sX[4][65];
    int tid = threadIdx.x;
    for (int i = tid; i < 4096; i += 256) {
        sWll[i] = Wll[i];
        sWlr[i] = Wlr[i];
    }
    __syncthreads();
    int g = tid >> 6, j = tid & 63;
    float gj = bng[j], bj = bnb[j], mj = bnm[j];
    float rj = rsqrtf(bnv[j] + EPSF);
    float blj = bll[j];
    int base = blockIdx.x * 64;
    for (int nb = 0; nb < 64; nb += 4) {
        int node = base + nb + g;
        bool valid = node < n_nodes;
        if (valid) {
            sA[g][j] = agg[(size_t)node * H + j];
            sX[g][j] = x_in[(size_t)node * H + j];
        }
        __syncthreads();
        if (valid) {
            float accA = 0.f, accX = 0.f;
#pragma unroll
            for (int k = 0; k < 64; ++k) {
                accA = fmaf(sA[g][k], sWll[k * 64 + j], accA);
                accX = fmaf(sX[g][k], sWlr[k * 64 + j], accX);
            }
            float val = accA + blj + accX;
            val = (val - mj) * rj * gj + bj;
            x_out[(size_t)node * H + j] = fmaxf(val, 0.f);
        }
        __syncthreads();
    }
}

// ---------------- MLP head: 64 pairs per block (16 passes of 4) ----------------
__global__ __launch_bounds__(256) void mlp_kernel(
    const int* __restrict__ eli,
    const float* __restrict__ xu, const float* __restrict__ xi,
    const float* __restrict__ fc1w, const float* __restrict__ fc1b,
    const float* __restrict__ fc2w, const float* __restrict__ fc2b,
    float* __restrict__ out, int n)
{
    __shared__ float sW1[128 * 64];
    __shared__ float sU[4][65];
    __shared__ float sI[4][65];
    int tid = threadIdx.x;
    for (int i = tid; i < 8192; i += 256) sW1[i] = fc1w[i];
    __syncthreads();
    int w = tid >> 6, j = tid & 63;
    int base = blockIdx.x * 64;
    for (int pp = 0; pp < 64; pp += 4) {
        int p = base + pp + w;
        bool valid = p < n;
        if (valid) {
            int ui = eli[p];
            int ii = eli[NP + p];
            sU[w][j] = xu[(size_t)ui * H + j];
            sI[w][j] = xi[(size_t)ii * H + j];
        }
        __syncthreads();
        float h = 0.f;
        if (valid) {
            float acc = fc1b[j];
#pragma unroll
            for (int k = 0; k < 64; ++k) acc = fmaf(sU[w][k], sW1[k * 64 + j], acc);
#pragma unroll
            for (int k = 0; k < 64; ++k) acc = fmaf(sI[w][k], sW1[(64 + k) * 64 + j], acc);
            h = fmaxf(acc, 0.f);
        }
        float p0 = h * fc2w[j * 4 + 0];
        float p1 = h * fc2w[j * 4 + 1];
        float p2 = h * fc2w[j * 4 + 2];
        float p3 = h * fc2w[j * 4 + 3];
#pragma unroll
        for (int offm = 32; offm >= 1; offm >>= 1) {
            p0 += __shfl_xor(p0, offm);
            p1 += __shfl_xor(p1, offm);
            p2 += __shfl_xor(p2, offm);
            p3 += __shfl_xor(p3, offm);
        }
        if (valid && j == 0) {
            out[(size_t)p * 4 + 0] = p0 + fc2b[0];
            out[(size_t)p * 4 + 1] = p1 + fc2b[1];
            out[(size_t)p * 4 + 2] = p2 + fc2b[2];
            out[(size_t)p * 4 + 3] = p3 + fc2b[3];
        }
        __syncthreads();
    }
}

extern "C" void kernel_launch(void* const* d_in, const int* in_sizes, int n_in,
                              void* d_out, int out_size, void* d_ws, size_t ws_size,
                              hipStream_t stream) {
    const int*   edge_index = (const int*)d_in[0];
    const int*   eli        = (const int*)d_in[1];
    const float* user_emb   = (const float*)d_in[2];
    const float* item_emb   = (const float*)d_in[3];
    const float* u_ll_w     = (const float*)d_in[4];
    const float* u_ll_b     = (const float*)d_in[5];
    const float* u_lr_w     = (const float*)d_in[6];
    const float* i_ll_w     = (const float*)d_in[7];
    const float* i_ll_b     = (const float*)d_in[8];
    const float* i_lr_w     = (const float*)d_in[9];
    const float* u_bn_g     = (const float*)d_in[10];
    const float* u_bn_b     = (const float*)d_in[11];
    const float* u_bn_m     = (const float*)d_in[12];
    const float* u_bn_v     = (const float*)d_in[13];
    const float* i_bn_g     = (const float*)d_in[14];
    const float* i_bn_b     = (const float*)d_in[15];
    const float* i_bn_m     = (const float*)d_in[16];
    const float* i_bn_v     = (const float*)d_in[17];
    const float* fc1_w      = (const float*)d_in[18];
    const float* fc1_b      = (const float*)d_in[19];
    const float* fc2_w      = (const float*)d_in[20];
    const float* fc2_b      = (const float*)d_in[21];
    float* out = (float*)d_out;

    const int* src = edge_index;
    const int* dst = edge_index + NE;

    // workspace layout (floats first for 16B alignment)
    char* w = (char*)d_ws;
    float* bufA_u = (float*)w;  w += (size_t)NU * H * 4;
    float* bufA_i = (float*)w;  w += (size_t)NI * H * 4;
    float* bufB_u = (float*)w;  w += (size_t)NU * H * 4;
    float* bufB_i = (float*)w;  w += (size_t)NI * H * 4;
    int* adj  = (int*)w;        w += (size_t)2 * NE * 4;
    int* off  = (int*)w;        w += (size_t)(NN + 1) * 4;
    int* cnt  = (int*)w;        w += (size_t)NN * 4;      // reused as cursor
    int* bsum = (int*)w;        w += 1024 * 4;
    int* bpre = (int*)w;        w += 1024 * 4;

    const int scan_blocks = (NN + 1023) / 1024;  // 391

    // ---- CSR build ----
    hipMemsetAsync(cnt, 0, (size_t)NN * 4, stream);
    count_kernel<<<(NE + 255) / 256, 256, 0, stream>>>(src, dst, cnt, NE);
    scan1_kernel<<<scan_blocks, 1024, 0, stream>>>(cnt, off, bsum, NN);
    scan2_kernel<<<1, 1024, 0, stream>>>(bsum, bpre, scan_blocks);
    scan3_kernel<<<scan_blocks, 1024, 0, stream>>>(off, bpre, NN);
    hipMemsetAsync(cnt, 0, (size_t)NN * 4, stream);
    fill_kernel<<<(NE + 255) / 256, 256, 0, stream>>>(src, dst, off, cnt, adj, NE);

    const int pull_blocks = NN / 4;  // 4 waves per block, one node per wave

    // ---- layer 0 (reads embeddings from d_in) ----
    pull_kernel<<<pull_blocks, 256, 0, stream>>>(
        off, adj, user_emb, item_emb, bufA_u, bufA_i);
    update_kernel<<<(NU + 63) / 64, 256, 0, stream>>>(
        bufA_u, user_emb, bufA_u,
        u_ll_w, u_ll_b, u_lr_w,
        u_bn_g, u_bn_b, u_bn_m, u_bn_v, NU);
    update_kernel<<<(NI + 63) / 64, 256, 0, stream>>>(
        bufA_i, item_emb, bufA_i,
        i_ll_w, i_ll_b, i_lr_w,
        i_bn_g, i_bn_b, i_bn_m, i_bn_v, NI);

    // ---- layer 1 ----
    pull_kernel<<<pull_blocks, 256, 0, stream>>>(
        off, adj, bufA_u, bufA_i, bufB_u, bufB_i);
    update_kernel<<<(NU + 63) / 64, 256, 0, stream>>>(
        bufB_u, bufA_u, bufB_u,
        u_ll_w + H * H, u_ll_b + H, u_lr_w + H * H,
        u_bn_g + H, u_bn_b + H, u_bn_m + H, u_bn_v + H, NU);
    update_kernel<<<(NI + 63) / 64, 256, 0, stream>>>(
        bufB_i, bufA_i, bufB_i,
        i_ll_w + H * H, i_ll_b + H, i_lr_w + H * H,
        i_bn_g + H, i_bn_b + H, i_bn_m + H, i_bn_v + H, NI);

    // ---- MLP head ----
    mlp_kernel<<<(NP + 63) / 64, 256, 0, stream>>>(
        eli, bufB_u, bufB_i, fc1_w, fc1_b, fc2_w, fc2_b, out, NP);
}